// Round 5
// baseline (199.286 us; speedup 1.0000x reference)
//
#include <hip/hip_runtime.h>
#include <hip/hip_bf16.h>
#include <stdint.h>

#define M_TOT 16384
#define N_TOT 3072
#define K_TOT 768

#define BM 256
#define BN 256
#define BK 32
#define NT (K_TOT / BK)   // 24 K-tiles

typedef __attribute__((ext_vector_type(8))) short short8;
typedef __attribute__((ext_vector_type(4))) float f32x4;

__device__ __forceinline__ unsigned short f2bf(float f) {
    union { float f; unsigned u; } v;
    v.f = f;
    unsigned r = v.u + 0x7FFFu + ((v.u >> 16) & 1u);  // round-to-nearest-even
    return (unsigned short)(r >> 16);
}

// ---------------- kernel 1: x fp32 -> bf16 (vectorized) ----------------------
__global__ __launch_bounds__(256) void cvt_x_kernel(const float* __restrict__ x,
                                                    unsigned short* __restrict__ xb,
                                                    int n8) {
    int i = blockIdx.x * blockDim.x + threadIdx.x;
    int stride = gridDim.x * blockDim.x;
    const float4* xv = reinterpret_cast<const float4*>(x);
    uint4* ov = reinterpret_cast<uint4*>(xb);
    for (; i < n8; i += stride) {
        float4 a = xv[2 * i], b = xv[2 * i + 1];
        uint4 o;
        o.x = (unsigned)f2bf(a.x) | ((unsigned)f2bf(a.y) << 16);
        o.y = (unsigned)f2bf(a.z) | ((unsigned)f2bf(a.w) << 16);
        o.z = (unsigned)f2bf(b.x) | ((unsigned)f2bf(b.y) << 16);
        o.w = (unsigned)f2bf(b.z) | ((unsigned)f2bf(b.w) << 16);
        ov[i] = o;
    }
}

// ---------------- kernel 2a: W_tilde = A @ B (2048x1152x64, fp32) ------------
__global__ __launch_bounds__(256) void wtilde_gemm_kernel(const float* __restrict__ Af,
                                                          const float* __restrict__ Bf,
                                                          float* __restrict__ Wtmp) {
    __shared__ float As[64][68];
    __shared__ float Bs[64][68];
    const int tid = threadIdx.x;
    const int bp = blockIdx.x / 18, bq = blockIdx.x % 18;
    const int p0 = bp * 64, q0 = bq * 64;
    {
        const int p = tid & 63, kb = tid >> 6;
        #pragma unroll
        for (int l = 0; l < 16; ++l) {
            int k = l * 4 + kb;
            As[k][p] = Af[(size_t)(p0 + p) * 64 + k];
        }
    }
    {
        #pragma unroll
        for (int l = 0; l < 4; ++l) {
            int idx = l * 256 + tid;
            int k = idx >> 4, c4 = (idx & 15) * 4;
            *reinterpret_cast<f32x4*>(&Bs[k][c4]) =
                *reinterpret_cast<const f32x4*>(&Bf[(size_t)k * 1152 + q0 + c4]);
        }
    }
    __syncthreads();
    float acc[4][4] = {};
    const int rb = (tid >> 4) * 4;
    const int cb = (tid & 15) * 4;
    #pragma unroll
    for (int k = 0; k < 64; ++k) {
        f32x4 a = *reinterpret_cast<const f32x4*>(&As[k][rb]);
        f32x4 b = *reinterpret_cast<const f32x4*>(&Bs[k][cb]);
        #pragma unroll
        for (int i = 0; i < 4; ++i)
            #pragma unroll
            for (int j = 0; j < 4; ++j)
                acc[i][j] = fmaf(a[i], b[j], acc[i][j]);
    }
    #pragma unroll
    for (int i = 0; i < 4; ++i) {
        f32x4 o = {acc[i][0], acc[i][1], acc[i][2], acc[i][3]};
        *reinterpret_cast<f32x4*>(&Wtmp[(size_t)(p0 + rb + i) * 1152 + q0 + cb]) = o;
    }
}

// ---------------- kernel 2b: Kronecker permute + Sparse + bf16 + transpose ---
__global__ __launch_bounds__(256) void permute_w_kernel(const float* __restrict__ Wtmp,
                                                        const float* __restrict__ Sp,
                                                        unsigned short* __restrict__ Wt) {
    __shared__ float T[64][65];
    const int tid = threadIdx.x;
    const int r0 = (blockIdx.x % 12) * 64;
    const int c0 = (blockIdx.x / 12) * 64;
    #pragma unroll
    for (int l = 0; l < 16; ++l) {
        int i = l * 4 + (tid >> 6);
        int j = tid & 63;
        int r = r0 + i, c = c0 + j;
        int m1 = r / 24, m2 = r - m1 * 24;
        int n1 = c / 48, n2 = c - n1 * 48;
        T[i][j] = Wtmp[(size_t)(m1 * 64 + n1) * 1152 + m2 * 48 + n2]
                + Sp[(size_t)r * 3072 + c];
    }
    __syncthreads();
    #pragma unroll
    for (int u0 = 0; u0 < 2; ++u0) {
        int u = u0 * 256 + tid;
        int jj = u >> 3;
        int ii = u & 7;
        unsigned w[4];
        #pragma unroll
        for (int t = 0; t < 4; ++t) {
            unsigned lo = f2bf(T[ii * 8 + 2 * t][jj]);
            unsigned hi = f2bf(T[ii * 8 + 2 * t + 1][jj]);
            w[t] = lo | (hi << 16);
        }
        uint4 o = {w[0], w[1], w[2], w[3]};
        *reinterpret_cast<uint4*>(&Wt[(size_t)(c0 + jj) * 768 + r0 + ii * 8]) = o;
    }
}

// ---------------- kernel 3: 256x256 GEMM, A in LDS / B in registers ----------
// A  : [16384][768] bf16 row-major; Bt : [3072][768] bf16 row-major
// C = A@Bt^T + bias.  8 waves (2Mx4N), BK=32, 4 A-only LDS buffers (64KB),
// B fragments prefetched global->VGPR one K-tile ahead, counted vmcnt.
__device__ __forceinline__ void gld16(const void* g, void* l) {
    __builtin_amdgcn_global_load_lds(
        (const __attribute__((address_space(1))) void*)g,
        (__attribute__((address_space(3))) void*)l, 16, 0, 0);
}

__global__ __launch_bounds__(512, 2) void gemm_bt_kernel(const unsigned short* __restrict__ A,
                                                         const unsigned short* __restrict__ Bt,
                                                         const float* __restrict__ bias,
                                                         float* __restrict__ C) {
    __shared__ unsigned short As[4][BM * BK];   // 4 x 16KB = 64KB

    const int tid = threadIdx.x;
    const int lane = tid & 63;
    const int wid = tid >> 6;      // 0..7
    const int wr = wid >> 2;       // 0..1  (M half)
    const int wc = wid & 3;        // 0..3  (N quarter)

    // XCD-aware swizzle: 768 blocks = 8 XCDs x 96
    const int wg = (blockIdx.x & 7) * 96 + (blockIdx.x >> 3);
    const int bm = wg / (N_TOT / BN), bn = wg % (N_TOT / BN);
    const int brow = bm * BM, bcol = bn * BN;

    // ---- A staging (linear LDS dest, pre-swizzled global source) ------------
    // phys 16B slot = logical slot ^ ((row>>1)&3), rows are 64B
    const int srow = tid >> 2;                                   // 0..127
    const int soff = (((tid & 3) ^ ((tid >> 3) & 3)) << 4);      // bytes
    const char* pA = (const char*)A + ((size_t)(brow + srow) * K_TOT) * 2 + soff;
    const size_t row128 = (size_t)128 * K_TOT * 2;
    const int tid16 = tid * 16;

#define STAGE_A(u) do { const char* s_ = pA + (size_t)(u) * (BK * 2);            \
        gld16(s_,          (char*)&As[(u) & 3][0] + tid16);                      \
        gld16(s_ + row128, (char*)&As[(u) & 3][0] + tid16 + 8192); } while (0)

    // ---- A fragment reads: phys byte = row*64 + ((js ^ ((row>>1)&3))<<4) ----
    const int la = lane & 15;
    const int swb = (((lane >> 4) ^ ((lane >> 1) & 3)) << 4);
#define FRAG_A(bu, r) (*(const short8*)((const char*)&As[bu][0] + (r) * 64 + swb))

    // ---- B fragment pointers (global->VGPR, one tile ahead) -----------------
    // b[n] elems j: Bt[bcol + wc*64 + n*16 + la][k0 + (lane>>4)*8 + j]
    const int bcolw = wc * 64;
    const short8* pB_[4];
    #pragma unroll
    for (int n = 0; n < 4; ++n)
        pB_[n] = reinterpret_cast<const short8*>(
            Bt + (size_t)(bcol + bcolw + n * 16 + la) * K_TOT + (lane >> 4) * 8);
    // tile u -> element offset u*BK = u*32 elems = u*4 in short8 units

    f32x4 acc[8][4];
    #pragma unroll
    for (int m = 0; m < 8; ++m)
        #pragma unroll
        for (int n = 0; n < 4; ++n)
            acc[m][n] = (f32x4){0.f, 0.f, 0.f, 0.f};

    short8 bn_[4];
    // prologue: B(0) regs; stage A tiles 0,1,2; wait B(0)+A(0) (A1,A2 fly)
    #pragma unroll
    for (int n = 0; n < 4; ++n) bn_[n] = pB_[n][0];
    STAGE_A(0); STAGE_A(1); STAGE_A(2);
    asm volatile("s_waitcnt vmcnt(4)" ::: "memory");
    __builtin_amdgcn_s_barrier();

    const int arow = wr * 128;
    for (int t = 0; t < NT; ++t) {
        const int bu = t & 3;
        short8 a0[8], bc[4];
        #pragma unroll
        for (int n = 0; n < 4; ++n) bc[n] = bn_[n];            // B(t) -> consume
        #pragma unroll
        for (int m = 0; m < 8; ++m) a0[m] = FRAG_A(bu, arow + m * 16 + la);
        if (t < NT - 3) STAGE_A(t + 3);                        // +2 vm
        if (t < NT - 1) {                                      // B(t+1), +4 vm
            #pragma unroll
            for (int n = 0; n < 4; ++n) bn_[n] = pB_[n][(t + 1) * 4];
        }
        // counted waits: steady state keeps A(t+3):2 + B(t+1):4 = 6 in flight
        if (t < NT - 3)       asm volatile("s_waitcnt vmcnt(6)" ::: "memory");
        else if (t == NT - 3) asm volatile("s_waitcnt vmcnt(4)" ::: "memory");
        else if (t == NT - 2) asm volatile("s_waitcnt vmcnt(4)" ::: "memory");
        else                  asm volatile("s_waitcnt vmcnt(0)" ::: "memory");
        __builtin_amdgcn_s_barrier();
        asm volatile("s_waitcnt lgkmcnt(0)" ::: "memory");
        __builtin_amdgcn_sched_barrier(0);
        __builtin_amdgcn_s_setprio(1);
        #pragma unroll
        for (int m = 0; m < 8; ++m)
            #pragma unroll
            for (int n = 0; n < 4; ++n)
                acc[m][n] = __builtin_amdgcn_mfma_f32_16x16x32_bf16(
                    a0[m], bc[n], acc[m][n], 0, 0, 0);
        __builtin_amdgcn_s_setprio(0);
        __builtin_amdgcn_s_barrier();
    }

    // ---- epilogue: C/D layout col = lane&15, row = (lane>>4)*4 + j ----------
    const int rg = (lane >> 4) * 4;
    #pragma unroll
    for (int n = 0; n < 4; ++n) {
        const int gc = bcol + bcolw + n * 16 + la;
        const float bv = bias[gc];
        #pragma unroll
        for (int m = 0; m < 8; ++m) {
            const int gr = brow + arow + m * 16 + rg;
            #pragma unroll
            for (int j = 0; j < 4; ++j)
                C[(size_t)(gr + j) * N_TOT + gc] = acc[m][n][j] + bv;
        }
    }
#undef STAGE_A
#undef FRAG_A
}

extern "C" void kernel_launch(void* const* d_in, const int* in_sizes, int n_in,
                              void* d_out, int out_size, void* d_ws, size_t ws_size,
                              hipStream_t stream) {
    const float* x    = (const float*)d_in[0];
    const float* Af   = (const float*)d_in[1];  // [2048][64]
    const float* Bf   = (const float*)d_in[2];  // [64][1152]
    const float* Sp   = (const float*)d_in[3];  // [768][3072]
    const float* bias = (const float*)d_in[4];  // [3072]
    float* out = (float*)d_out;

    unsigned short* xb = (unsigned short*)d_ws;                 // 25,165,824 B
    unsigned short* wt = xb + (size_t)M_TOT * K_TOT;            // + 4,718,592 B
    // W_tilde scratch in d_out's head; GEMM overwrites all of d_out after.
    float* wtmp = (float*)d_out;                                // 9,437,184 B

    hipLaunchKernelGGL(cvt_x_kernel, dim3(2048), dim3(256), 0, stream,
                       x, xb, M_TOT * K_TOT / 8);
    hipLaunchKernelGGL(wtilde_gemm_kernel, dim3(32 * 18), dim3(256), 0, stream,
                       Af, Bf, wtmp);
    hipLaunchKernelGGL(permute_w_kernel, dim3(12 * 48), dim3(256), 0, stream,
                       wtmp, Sp, wt);
    hipLaunchKernelGGL(gemm_bt_kernel,
                       dim3((M_TOT / BM) * (N_TOT / BN)), dim3(512),
                       0, stream, xb, wt, bias, out);
}

// Round 6
// 157.690 us; speedup vs baseline: 1.2638x; 1.2638x over previous
//
#include <hip/hip_runtime.h>
#include <hip/hip_bf16.h>
#include <stdint.h>

#define M_TOT 16384
#define N_TOT 3072
#define K_TOT 768

#define BM 256
#define BN 256
#define BK 64
#define NT64 (K_TOT / BK)   // 12 K-tiles

typedef __attribute__((ext_vector_type(8))) short short8;
typedef __attribute__((ext_vector_type(4))) float f32x4;

__device__ __forceinline__ unsigned short f2bf(float f) {
    union { float f; unsigned u; } v;
    v.f = f;
    unsigned r = v.u + 0x7FFFu + ((v.u >> 16) & 1u);  // round-to-nearest-even
    return (unsigned short)(r >> 16);
}

// ---------------- kernel 1: x fp32 -> bf16 (vectorized) ----------------------
__global__ __launch_bounds__(256) void cvt_x_kernel(const float* __restrict__ x,
                                                    unsigned short* __restrict__ xb,
                                                    int n8) {
    int i = blockIdx.x * blockDim.x + threadIdx.x;
    int stride = gridDim.x * blockDim.x;
    const float4* xv = reinterpret_cast<const float4*>(x);
    uint4* ov = reinterpret_cast<uint4*>(xb);
    for (; i < n8; i += stride) {
        float4 a = xv[2 * i], b = xv[2 * i + 1];
        uint4 o;
        o.x = (unsigned)f2bf(a.x) | ((unsigned)f2bf(a.y) << 16);
        o.y = (unsigned)f2bf(a.z) | ((unsigned)f2bf(a.w) << 16);
        o.z = (unsigned)f2bf(b.x) | ((unsigned)f2bf(b.y) << 16);
        o.w = (unsigned)f2bf(b.z) | ((unsigned)f2bf(b.w) << 16);
        ov[i] = o;
    }
}

// ---------------- kernel 2a: W_tilde = A @ B (2048x1152x64, fp32) ------------
__global__ __launch_bounds__(256) void wtilde_gemm_kernel(const float* __restrict__ Af,
                                                          const float* __restrict__ Bf,
                                                          float* __restrict__ Wtmp) {
    __shared__ float As[64][68];
    __shared__ float Bs[64][68];
    const int tid = threadIdx.x;
    const int bp = blockIdx.x / 18, bq = blockIdx.x % 18;
    const int p0 = bp * 64, q0 = bq * 64;
    {
        const int p = tid & 63, kb = tid >> 6;
        #pragma unroll
        for (int l = 0; l < 16; ++l) {
            int k = l * 4 + kb;
            As[k][p] = Af[(size_t)(p0 + p) * 64 + k];
        }
    }
    {
        #pragma unroll
        for (int l = 0; l < 4; ++l) {
            int idx = l * 256 + tid;
            int k = idx >> 4, c4 = (idx & 15) * 4;
            *reinterpret_cast<f32x4*>(&Bs[k][c4]) =
                *reinterpret_cast<const f32x4*>(&Bf[(size_t)k * 1152 + q0 + c4]);
        }
    }
    __syncthreads();
    float acc[4][4] = {};
    const int rb = (tid >> 4) * 4;
    const int cb = (tid & 15) * 4;
    #pragma unroll
    for (int k = 0; k < 64; ++k) {
        f32x4 a = *reinterpret_cast<const f32x4*>(&As[k][rb]);
        f32x4 b = *reinterpret_cast<const f32x4*>(&Bs[k][cb]);
        #pragma unroll
        for (int i = 0; i < 4; ++i)
            #pragma unroll
            for (int j = 0; j < 4; ++j)
                acc[i][j] = fmaf(a[i], b[j], acc[i][j]);
    }
    #pragma unroll
    for (int i = 0; i < 4; ++i) {
        f32x4 o = {acc[i][0], acc[i][1], acc[i][2], acc[i][3]};
        *reinterpret_cast<f32x4*>(&Wtmp[(size_t)(p0 + rb + i) * 1152 + q0 + cb]) = o;
    }
}

// ---------------- kernel 2b: Kronecker permute + Sparse + bf16 + transpose ---
__global__ __launch_bounds__(256) void permute_w_kernel(const float* __restrict__ Wtmp,
                                                        const float* __restrict__ Sp,
                                                        unsigned short* __restrict__ Wt) {
    __shared__ float T[64][65];
    const int tid = threadIdx.x;
    const int r0 = (blockIdx.x % 12) * 64;
    const int c0 = (blockIdx.x / 12) * 64;
    #pragma unroll
    for (int l = 0; l < 16; ++l) {
        int i = l * 4 + (tid >> 6);
        int j = tid & 63;
        int r = r0 + i, c = c0 + j;
        int m1 = r / 24, m2 = r - m1 * 24;
        int n1 = c / 48, n2 = c - n1 * 48;
        T[i][j] = Wtmp[(size_t)(m1 * 64 + n1) * 1152 + m2 * 48 + n2]
                + Sp[(size_t)r * 3072 + c];
    }
    __syncthreads();
    #pragma unroll
    for (int u0 = 0; u0 < 2; ++u0) {
        int u = u0 * 256 + tid;
        int jj = u >> 3;
        int ii = u & 7;
        unsigned w[4];
        #pragma unroll
        for (int t = 0; t < 4; ++t) {
            unsigned lo = f2bf(T[ii * 8 + 2 * t][jj]);
            unsigned hi = f2bf(T[ii * 8 + 2 * t + 1][jj]);
            w[t] = lo | (hi << 16);
        }
        uint4 o = {w[0], w[1], w[2], w[3]};
        *reinterpret_cast<uint4*>(&Wt[(size_t)(c0 + jj) * 768 + r0 + ii * 8]) = o;
    }
}

// ---------------- kernel 3: 256x256, BK=64, ONE barrier per K-tile -----------
// A  : [16384][768] bf16 row-major; Bt : [3072][768] bf16 row-major
// C = A@Bt^T + bias.  8 waves (2Mx4N), 2 LDS buffers (128KB), prefetch-1,
// no intra-tile barriers: 64 MFMA/wave between consecutive rendezvous.
__device__ __forceinline__ void gld16(const void* g, void* l) {
    __builtin_amdgcn_global_load_lds(
        (const __attribute__((address_space(1))) void*)g,
        (__attribute__((address_space(3))) void*)l, 16, 0, 0);
}

__global__ __launch_bounds__(512, 2) void gemm_bt_kernel(const unsigned short* __restrict__ A,
                                                         const unsigned short* __restrict__ Bt,
                                                         const float* __restrict__ bias,
                                                         float* __restrict__ C) {
    // [buf][256 rows][64 k] bf16: rows are 128B = 8 x 16B slots
    __shared__ unsigned short As[2][BM * BK];   // 2 x 32KB
    __shared__ unsigned short Bs[2][BN * BK];   // 2 x 32KB

    const int tid = threadIdx.x;
    const int lane = tid & 63;
    const int wid = tid >> 6;      // 0..7
    const int wr = wid >> 2;       // 0..1  (M half)
    const int wc = wid & 3;        // 0..3  (N quarter)

    // XCD swizzle: XCD x owns bm = 8x..8x+7 for all 12 bn (A-panels L2-resident)
    const int wg = (blockIdx.x & 7) * 96 + (blockIdx.x >> 3);
    const int bm = wg / (N_TOT / BN), bn = wg % (N_TOT / BN);
    const int brow = bm * BM, bcol = bn * BN;

    // ---- staging: linear LDS dest (tid*16 within 8KB round), swizzled source.
    // dest row (per round r) = r*64 + tid>>3, phys slot = tid&7
    // logical slot = phys ^ (row&7) = (tid&7) ^ ((tid>>3)&7)
    const int srow = tid >> 3;                                   // 0..63
    const int sslot = (tid & 7) ^ ((tid >> 3) & 7);              // 16B slot
    const char* pA = (const char*)A + ((size_t)(brow + srow) * K_TOT + sslot * 8) * 2;
    const char* pB = (const char*)Bt + ((size_t)(bcol + srow) * K_TOT + sslot * 8) * 2;
    const size_t rstep = (size_t)64 * K_TOT * 2;   // 64 rows of source
    const int tid16 = tid * 16;

    // tile t -> source byte offset t*BK*2 = t*128
#define STG_A(bu, t, r) gld16(pA + (size_t)(r) * rstep + (size_t)(t) * 128,      \
        (char*)&As[bu][0] + (r) * 8192 + tid16)
#define STG_B(bu, t, r) gld16(pB + (size_t)(r) * rstep + (size_t)(t) * 128,      \
        (char*)&Bs[bu][0] + (r) * 8192 + tid16)

    // ---- fragment read: byte = row*128 + ((s ^ (row&7))<<4), s = kk*4 + g4
    const int la = lane & 15;
    const int g4 = lane >> 4;
#define FRAGRD(base, row, s) (*(const short8*)((const char*)(base) +             \
        (row) * 128 + ((((s) ^ ((row) & 7))) << 4)))

    f32x4 acc[8][4];
    #pragma unroll
    for (int m = 0; m < 8; ++m)
        #pragma unroll
        for (int n = 0; n < 4; ++n)
            acc[m][n] = (f32x4){0.f, 0.f, 0.f, 0.f};

    // prologue: stage tile 0 into buf 0, publish
    #pragma unroll
    for (int r = 0; r < 4; ++r) { STG_A(0, 0, r); STG_B(0, 0, r); }
    asm volatile("s_waitcnt vmcnt(0)" ::: "memory");
    __builtin_amdgcn_s_barrier();
    __builtin_amdgcn_sched_barrier(0);

    const int arow = wr * 128;
    const int bcolw = wc * 64;

    for (int t = 0; t < NT64; ++t) {
        const int bu = t & 1;
        const unsigned short* Ab = &As[bu][0];
        const unsigned short* Bb = &Bs[bu][0];
        const bool pf = (t + 1 < NT64);
        short8 a_[4], b_[4];

        // ---- cluster 0: prefetch 4 loads; kk=0, m0-3 ------------------------
        if (pf) { STG_A(bu ^ 1, t + 1, 0); STG_A(bu ^ 1, t + 1, 1);
                  STG_B(bu ^ 1, t + 1, 0); STG_B(bu ^ 1, t + 1, 1); }
        #pragma unroll
        for (int n = 0; n < 4; ++n) b_[n] = FRAGRD(Bb, bcolw + n * 16 + la, g4);
        #pragma unroll
        for (int m = 0; m < 4; ++m) a_[m] = FRAGRD(Ab, arow + m * 16 + la, g4);
        __builtin_amdgcn_s_setprio(1);
        #pragma unroll
        for (int m = 0; m < 4; ++m)
            #pragma unroll
            for (int n = 0; n < 4; ++n)
                acc[m][n] = __builtin_amdgcn_mfma_f32_16x16x32_bf16(
                    a_[m], b_[n], acc[m][n], 0, 0, 0);
        __builtin_amdgcn_s_setprio(0);

        // ---- cluster 1: prefetch 4 loads; kk=0, m4-7 ------------------------
        if (pf) { STG_A(bu ^ 1, t + 1, 2); STG_A(bu ^ 1, t + 1, 3);
                  STG_B(bu ^ 1, t + 1, 2); STG_B(bu ^ 1, t + 1, 3); }
        #pragma unroll
        for (int m = 0; m < 4; ++m) a_[m] = FRAGRD(Ab, arow + 64 + m * 16 + la, g4);
        __builtin_amdgcn_s_setprio(1);
        #pragma unroll
        for (int m = 0; m < 4; ++m)
            #pragma unroll
            for (int n = 0; n < 4; ++n)
                acc[4 + m][n] = __builtin_amdgcn_mfma_f32_16x16x32_bf16(
                    a_[m], b_[n], acc[4 + m][n], 0, 0, 0);
        __builtin_amdgcn_s_setprio(0);

        // ---- cluster 2: kk=1, m0-3 ------------------------------------------
        #pragma unroll
        for (int n = 0; n < 4; ++n) b_[n] = FRAGRD(Bb, bcolw + n * 16 + la, 4 + g4);
        #pragma unroll
        for (int m = 0; m < 4; ++m) a_[m] = FRAGRD(Ab, arow + m * 16 + la, 4 + g4);
        __builtin_amdgcn_s_setprio(1);
        #pragma unroll
        for (int m = 0; m < 4; ++m)
            #pragma unroll
            for (int n = 0; n < 4; ++n)
                acc[m][n] = __builtin_amdgcn_mfma_f32_16x16x32_bf16(
                    a_[m], b_[n], acc[m][n], 0, 0, 0);
        __builtin_amdgcn_s_setprio(0);

        // ---- cluster 3: kk=1, m4-7 ------------------------------------------
        #pragma unroll
        for (int m = 0; m < 4; ++m) a_[m] = FRAGRD(Ab, arow + 64 + m * 16 + la, 4 + g4);
        __builtin_amdgcn_s_setprio(1);
        #pragma unroll
        for (int m = 0; m < 4; ++m)
            #pragma unroll
            for (int n = 0; n < 4; ++n)
                acc[4 + m][n] = __builtin_amdgcn_mfma_f32_16x16x32_bf16(
                    a_[m], b_[n], acc[4 + m][n], 0, 0, 0);
        __builtin_amdgcn_s_setprio(0);

        // ---- tile rendezvous: publish tile t+1; free buf for tile t+2 -------
        if (pf) {
            asm volatile("s_waitcnt vmcnt(0)" ::: "memory");
            __builtin_amdgcn_s_barrier();
            __builtin_amdgcn_sched_barrier(0);
        }
    }

    // ---- epilogue: C/D layout col = lane&15, row = (lane>>4)*4 + j ----------
    const int rg = g4 * 4;
    #pragma unroll
    for (int n = 0; n < 4; ++n) {
        const int gc = bcol + bcolw + n * 16 + la;
        const float bv = bias[gc];
        #pragma unroll
        for (int m = 0; m < 8; ++m) {
            const int gr = brow + arow + m * 16 + rg;
            #pragma unroll
            for (int j = 0; j < 4; ++j)
                C[(size_t)(gr + j) * N_TOT + gc] = acc[m][n][j] + bv;
        }
    }
#undef STG_A
#undef STG_B
#undef FRAGRD
}

extern "C" void kernel_launch(void* const* d_in, const int* in_sizes, int n_in,
                              void* d_out, int out_size, void* d_ws, size_t ws_size,
                              hipStream_t stream) {
    const float* x    = (const float*)d_in[0];
    const float* Af   = (const float*)d_in[1];  // [2048][64]
    const float* Bf   = (const float*)d_in[2];  // [64][1152]
    const float* Sp   = (const float*)d_in[3];  // [768][3072]
    const float* bias = (const float*)d_in[4];  // [3072]
    float* out = (float*)d_out;

    unsigned short* xb = (unsigned short*)d_ws;                 // 25,165,824 B
    unsigned short* wt = xb + (size_t)M_TOT * K_TOT;            // + 4,718,592 B
    // W_tilde scratch in d_out's head; GEMM overwrites all of d_out after.
    float* wtmp = (float*)d_out;                                // 9,437,184 B

    hipLaunchKernelGGL(cvt_x_kernel, dim3(2048), dim3(256), 0, stream,
                       x, xb, M_TOT * K_TOT / 8);
    hipLaunchKernelGGL(wtilde_gemm_kernel, dim3(32 * 18), dim3(256), 0, stream,
                       Af, Bf, wtmp);
    hipLaunchKernelGGL(permute_w_kernel, dim3(12 * 48), dim3(256), 0, stream,
                       wtmp, Sp, wt);
    hipLaunchKernelGGL(gemm_bt_kernel,
                       dim3((M_TOT / BM) * (N_TOT / BN)), dim3(512),
                       0, stream, xb, wt, bias, out);
}